// Round 7
// baseline (307.876 us; speedup 1.0000x reference)
//
#include <hip/hip_runtime.h>
#include <hip/hip_bf16.h>

#define NNODES 65536
#define NEDGES 262144
#define BATCH  64
#define HDIM   256
#define NSLAB  8
#define NPB    128          // nodes per k_gemm block -> 512 blocks

// ---------------------------------------------------------------------------
// K1: per-node u[n] = Wf[0:H] . x[n],  v[n] = Wf[H:2H] . x[n]
//     one wave per node, float4 per lane (64*16B = 1KB coalesced row read)
// ---------------------------------------------------------------------------
__global__ __launch_bounds__(256) void k_uv(
    const float* __restrict__ hidden, const int* __restrict__ node_idx,
    const float* __restrict__ Wf, float* __restrict__ u, float* __restrict__ v) {
  int gw   = (blockIdx.x * 256 + threadIdx.x) >> 6;   // global wave = node
  int lane = threadIdx.x & 63;
  if (gw >= NNODES) return;
  const float4* xr = (const float4*)(hidden + (size_t)node_idx[gw] * HDIM);
  float4 xv = xr[lane];
  float4 wa = ((const float4*)Wf)[lane];
  float4 wb = ((const float4*)Wf)[64 + lane];
  float su = xv.x*wa.x + xv.y*wa.y + xv.z*wa.z + xv.w*wa.w;
  float sv = xv.x*wb.x + xv.y*wb.y + xv.z*wb.z + xv.w*wb.w;
  #pragma unroll
  for (int off = 32; off > 0; off >>= 1) {
    su += __shfl_down(su, off);
    sv += __shfl_down(sv, off);
  }
  if (lane == 0) { u[gw] = su; v[gw] = sv; }
}

// ---------------------------------------------------------------------------
// K2: per-edge filter weight w_e = sigmoid(u[row]+v[col]+bf); deg[col] += w_e
// ---------------------------------------------------------------------------
__global__ __launch_bounds__(256) void k_edge_w(
    const int* __restrict__ ei, const float* __restrict__ u,
    const float* __restrict__ v, const float* __restrict__ bf,
    float* __restrict__ wbuf, float* __restrict__ deg) {
  int e = blockIdx.x * 256 + threadIdx.x;
  if (e >= NEDGES) return;
  int r = ei[e], c = ei[NEDGES + e];
  float t = u[r] + v[c] + bf[0];
  float w = 1.0f / (1.0f + __expf(-t));
  wbuf[e] = w;
  unsafeAtomicAdd(&deg[c], w);            // random addrs, ~4/address: fine
}

// ---------------------------------------------------------------------------
// K3: dis[n] = rsqrt(deg[n]+1); self-loop weight into t. NO atomics.
// ---------------------------------------------------------------------------
__global__ __launch_bounds__(256) void k_dis(
    const int* __restrict__ node_batch, const float* __restrict__ deg,
    float* __restrict__ dis, float* __restrict__ t) {
  int n = blockIdx.x * 256 + threadIdx.x;
  if (n >= NNODES) return;
  float dn = rsqrtf(deg[n] + 1.0f);
  dis[n] = dn;
  t[(size_t)n * BATCH + node_batch[n]] = dn * dn;
}

// ---------------------------------------------------------------------------
// K3b: counts via binary search on the SORTED node_batch (64 threads total).
// ---------------------------------------------------------------------------
__device__ __forceinline__ int lower_bound_batch(const int* nb, int key) {
  int lo = 0, hi = NNODES;
  while (lo < hi) {
    int mid = (lo + hi) >> 1;
    if (nb[mid] < key) lo = mid + 1; else hi = mid;
  }
  return lo;
}

__global__ __launch_bounds__(64) void k_cnt(
    const int* __restrict__ node_batch, int* __restrict__ cnt) {
  int b = threadIdx.x;   // 0..63
  int s0 = lower_bound_batch(node_batch, b);
  int s1 = lower_bound_batch(node_batch, b + 1);
  cnt[b] = s1 - s0;
}

// ---------------------------------------------------------------------------
// K4: scatter edge coefficients into t[row][batch[col]] (thread-per-edge).
// ---------------------------------------------------------------------------
__global__ __launch_bounds__(256) void k_t(
    const int* __restrict__ ei, const int* __restrict__ node_batch,
    const float* __restrict__ wbuf, const float* __restrict__ dis,
    float* __restrict__ t) {
  int e = blockIdx.x * 256 + threadIdx.x;
  if (e >= NEDGES) return;
  int r = ei[e], c = ei[NEDGES + e];
  float coeff = dis[r] * wbuf[e] * dis[c];
  int b = node_batch[c];
  unsafeAtomicAdd(&t[(size_t)r * BATCH + b], coeff);
}

// ---------------------------------------------------------------------------
// K5: part[b][j] += sum_n t[n][b] * x[n][j]
//     TRANSPOSED mapping (the R5 fix): lane = j-quad -> one wave-instr loads
//     the ENTIRE 1KB x row coalesced; wave w owns b in [4w,4w+4) and reads
//     t[n][4w..4w+3] as ONE wave-uniform float4 (scalarizable). Per node per
//     wave: 1 VMEM + 1 uniform load + 16 FMA (vs 80 VMEM/block-node before).
//     Explicit pipeline: nid 4 ahead, x-row / t-row 2 ahead (~50 VGPR).
//     Flush: lane-contiguous atomics into 8 partial slabs, [b][j] layout.
// ---------------------------------------------------------------------------
__global__ __launch_bounds__(1024) void k_gemm(
    const float* __restrict__ hidden, const int* __restrict__ node_idx,
    const float* __restrict__ t, float* __restrict__ part) {
  int lane = threadIdx.x & 63;              // j = 4*lane + c
  int w    = threadIdx.x >> 6;              // 0..15 -> b = 4*w + b'
  int n0   = blockIdx.x * NPB;
  float acc[4][4] = {{0.f}};                // [b'][c]

  // pipeline state: xA/tA = node i (ready), xB/tB = node i+1 (in flight),
  // nidC/nidD = indices for nodes i+2, i+3.
  int nidA = node_idx[n0];
  int nidB = node_idx[n0 + 1];
  int nidC = node_idx[n0 + 2];
  int nidD = node_idx[n0 + 3];
  float4 xA = *((const float4*)(hidden + (size_t)nidA * HDIM) + lane);
  float4 xB = *((const float4*)(hidden + (size_t)nidB * HDIM) + lane);
  float4 tA = *(const float4*)(t + (size_t)n0 * BATCH + 4 * w);
  float4 tB = *(const float4*)(t + (size_t)(n0 + 1) * BATCH + 4 * w);

  #pragma unroll 2
  for (int i = 0; i < NPB; ++i) {
    int ip2 = min(i + 2, NPB - 1);
    int ip4 = min(i + 4, NPB - 1);
    // issue loads for node i+2; index for node i+4
    float4 xN = *((const float4*)(hidden + (size_t)nidC * HDIM) + lane);
    float4 tN = *(const float4*)(t + (size_t)(n0 + ip2) * BATCH + 4 * w);
    int nidN  = node_idx[n0 + ip4];
    // compute node i
    acc[0][0] = fmaf(tA.x, xA.x, acc[0][0]);
    acc[0][1] = fmaf(tA.x, xA.y, acc[0][1]);
    acc[0][2] = fmaf(tA.x, xA.z, acc[0][2]);
    acc[0][3] = fmaf(tA.x, xA.w, acc[0][3]);
    acc[1][0] = fmaf(tA.y, xA.x, acc[1][0]);
    acc[1][1] = fmaf(tA.y, xA.y, acc[1][1]);
    acc[1][2] = fmaf(tA.y, xA.z, acc[1][2]);
    acc[1][3] = fmaf(tA.y, xA.w, acc[1][3]);
    acc[2][0] = fmaf(tA.z, xA.x, acc[2][0]);
    acc[2][1] = fmaf(tA.z, xA.y, acc[2][1]);
    acc[2][2] = fmaf(tA.z, xA.z, acc[2][2]);
    acc[2][3] = fmaf(tA.z, xA.w, acc[2][3]);
    acc[3][0] = fmaf(tA.w, xA.x, acc[3][0]);
    acc[3][1] = fmaf(tA.w, xA.y, acc[3][1]);
    acc[3][2] = fmaf(tA.w, xA.z, acc[3][2]);
    acc[3][3] = fmaf(tA.w, xA.w, acc[3][3]);
    // rotate pipeline
    xA = xB; xB = xN; tA = tB; tB = tN;
    nidC = nidD; nidD = nidN;
  }

  float* myp = part + (size_t)(blockIdx.x & (NSLAB - 1)) * (BATCH * HDIM);
  #pragma unroll
  for (int bi = 0; bi < 4; ++bi) {
    #pragma unroll
    for (int c = 0; c < 4; ++c)
      unsafeAtomicAdd(&myp[(size_t)(4 * w + bi) * HDIM + 4 * lane + c],
                      acc[bi][c]);
  }
}

// ---------------------------------------------------------------------------
// K5b: sum the 8 slabs -> agg[b][j]
// ---------------------------------------------------------------------------
__global__ __launch_bounds__(256) void k_reduce(
    const float* __restrict__ part, float* __restrict__ agg) {
  int i = blockIdx.x * 256 + threadIdx.x;   // 0..16383
  float s = 0.f;
  #pragma unroll
  for (int k = 0; k < NSLAB; ++k) s += part[(size_t)k * (BATCH * HDIM) + i];
  agg[i] = s;
}

// ---------------------------------------------------------------------------
// K6: one block per batch b.
//     pooled[k] = (Wc[k,:] . agg[b,:]) / cnt[b] + bc[k]
//     out[b][h] = tanh(Wd[h,:] . pooled + bd[h])
// ---------------------------------------------------------------------------
__global__ __launch_bounds__(256) void k_final(
    const float* __restrict__ agg, const int* __restrict__ cnt,
    const float* __restrict__ Wc, const float* __restrict__ bc,
    const float* __restrict__ Wd, const float* __restrict__ bd,
    float* __restrict__ out) {
  __shared__ float s_in[HDIM];
  __shared__ float s_mid[HDIM];
  int b = blockIdx.x, tid = threadIdx.x;
  s_in[tid] = agg[(size_t)b * HDIM + tid];     // coalesced row read
  __syncthreads();
  int lane = tid & 63, wid = tid >> 6;
  float inv = 1.0f / fmaxf((float)cnt[b], 1.0f);
  for (int kk = 0; kk < 64; ++kk) {
    int k = wid * 64 + kk;
    float4 wv = ((const float4*)(Wc + (size_t)k * HDIM))[lane];
    float4 av = ((const float4*)s_in)[lane];
    float p = wv.x*av.x + wv.y*av.y + wv.z*av.z + wv.w*av.w;
    #pragma unroll
    for (int off = 32; off > 0; off >>= 1) p += __shfl_down(p, off);
    if (lane == 0) s_mid[k] = p * inv + bc[k];
  }
  __syncthreads();
  for (int kk = 0; kk < 64; ++kk) {
    int k = wid * 64 + kk;
    float4 wv = ((const float4*)(Wd + (size_t)k * HDIM))[lane];
    float4 av = ((const float4*)s_mid)[lane];
    float p = wv.x*av.x + wv.y*av.y + wv.z*av.z + wv.w*av.w;
    #pragma unroll
    for (int off = 32; off > 0; off >>= 1) p += __shfl_down(p, off);
    if (lane == 0) out[b * HDIM + k] = tanhf(p + bd[k]);
  }
}

// ---------------------------------------------------------------------------
extern "C" void kernel_launch(void* const* d_in, const int* in_sizes, int n_in,
                              void* d_out, int out_size, void* d_ws, size_t ws_size,
                              hipStream_t stream) {
  const float* hidden     = (const float*)d_in[0];
  const int*   node_idx   = (const int*)  d_in[1];
  const int*   ei         = (const int*)  d_in[2];
  const int*   node_batch = (const int*)  d_in[3];
  const float* Wf         = (const float*)d_in[4];
  const float* bf         = (const float*)d_in[5];
  const float* Wc         = (const float*)d_in[6];
  const float* bc         = (const float*)d_in[7];
  const float* Wd         = (const float*)d_in[8];
  const float* bd         = (const float*)d_in[9];
  float* out = (float*)d_out;

  // workspace layout (floats)
  float* ws   = (float*)d_ws;
  float* t    = ws;                               // 4,194,304
  float* agg  = t + (size_t)NNODES * BATCH;       // 16,384  ([b][j])
  float* deg  = agg + BATCH * HDIM;               // 65,536
  int*   cnt  = (int*)(deg + NNODES);             // 64
  float* u    = (float*)(cnt + 64);               // 65,536
  float* v    = u + NNODES;                       // 65,536
  float* dis  = v + NNODES;                       // 65,536
  float* wbuf = dis + NNODES;                     // 262,144
  float* part = wbuf + NEDGES;                    // NSLAB*16,384 = 131,072

  // zero t | agg | deg | cnt (contiguous) and the partial slabs
  (void)hipMemsetAsync(t, 0,
      ((size_t)NNODES * BATCH + BATCH * HDIM + NNODES + 64) * sizeof(float),
      stream);
  (void)hipMemsetAsync(part, 0, (size_t)NSLAB * BATCH * HDIM * sizeof(float), stream);

  k_uv    <<<NNODES / 4,   256,  0, stream>>>(hidden, node_idx, Wf, u, v);
  k_edge_w<<<NEDGES / 256, 256,  0, stream>>>(ei, u, v, bf, wbuf, deg);
  k_dis   <<<NNODES / 256, 256,  0, stream>>>(node_batch, deg, dis, t);
  k_cnt   <<<1,            64,   0, stream>>>(node_batch, cnt);
  k_t     <<<NEDGES / 256, 256,  0, stream>>>(ei, node_batch, wbuf, dis, t);
  k_gemm  <<<NNODES / NPB, 1024, 0, stream>>>(hidden, node_idx, t, part);
  k_reduce<<<BATCH * HDIM / 256, 256, 0, stream>>>(part, agg);
  k_final <<<BATCH,        256,  0, stream>>>(agg, cnt, Wc, bc, Wd, bd, out);
}

// Round 8
// 183.085 us; speedup vs baseline: 1.6816x; 1.6816x over previous
//
#include <hip/hip_runtime.h>
#include <hip/hip_bf16.h>

#define NNODES 65536
#define NEDGES 262144
#define BATCH  64
#define HDIM   256
#define NPB    128          // nodes per k_gemm block -> 512 blocks
#define CK     16           // nodes per LDS chunk
#define NC     (NPB / CK)   // 8 chunks per block

// ---------------------------------------------------------------------------
// K1: per-node u[n] = Wf[0:H] . x[n],  v[n] = Wf[H:2H] . x[n]
// ---------------------------------------------------------------------------
__global__ __launch_bounds__(256) void k_uv(
    const float* __restrict__ hidden, const int* __restrict__ node_idx,
    const float* __restrict__ Wf, float* __restrict__ u, float* __restrict__ v) {
  int gw   = (blockIdx.x * 256 + threadIdx.x) >> 6;   // global wave = node
  int lane = threadIdx.x & 63;
  if (gw >= NNODES) return;
  const float4* xr = (const float4*)(hidden + (size_t)node_idx[gw] * HDIM);
  float4 xv = xr[lane];
  float4 wa = ((const float4*)Wf)[lane];
  float4 wb = ((const float4*)Wf)[64 + lane];
  float su = xv.x*wa.x + xv.y*wa.y + xv.z*wa.z + xv.w*wa.w;
  float sv = xv.x*wb.x + xv.y*wb.y + xv.z*wb.z + xv.w*wb.w;
  #pragma unroll
  for (int off = 32; off > 0; off >>= 1) {
    su += __shfl_down(su, off);
    sv += __shfl_down(sv, off);
  }
  if (lane == 0) { u[gw] = su; v[gw] = sv; }
}

// ---------------------------------------------------------------------------
// K2: per-edge filter weight w_e = sigmoid(u[row]+v[col]+bf); deg[col] += w_e
// ---------------------------------------------------------------------------
__global__ __launch_bounds__(256) void k_edge_w(
    const int* __restrict__ ei, const float* __restrict__ u,
    const float* __restrict__ v, const float* __restrict__ bf,
    float* __restrict__ wbuf, float* __restrict__ deg) {
  int e = blockIdx.x * 256 + threadIdx.x;
  if (e >= NEDGES) return;
  int r = ei[e], c = ei[NEDGES + e];
  float t = u[r] + v[c] + bf[0];
  float w = 1.0f / (1.0f + __expf(-t));
  wbuf[e] = w;
  unsafeAtomicAdd(&deg[c], w);
}

// ---------------------------------------------------------------------------
// K3: dis[n] = rsqrt(deg[n]+1); self-loop weight into t. NO atomics.
// ---------------------------------------------------------------------------
__global__ __launch_bounds__(256) void k_dis(
    const int* __restrict__ node_batch, const float* __restrict__ deg,
    float* __restrict__ dis, float* __restrict__ t) {
  int n = blockIdx.x * 256 + threadIdx.x;
  if (n >= NNODES) return;
  float dn = rsqrtf(deg[n] + 1.0f);
  dis[n] = dn;
  t[(size_t)n * BATCH + node_batch[n]] = dn * dn;
}

// ---------------------------------------------------------------------------
// K3b: counts via binary search on the SORTED node_batch (64 threads total).
// ---------------------------------------------------------------------------
__device__ __forceinline__ int lower_bound_batch(const int* nb, int key) {
  int lo = 0, hi = NNODES;
  while (lo < hi) {
    int mid = (lo + hi) >> 1;
    if (nb[mid] < key) lo = mid + 1; else hi = mid;
  }
  return lo;
}

__global__ __launch_bounds__(64) void k_cnt(
    const int* __restrict__ node_batch, int* __restrict__ cnt) {
  int b = threadIdx.x;   // 0..63
  int s0 = lower_bound_batch(node_batch, b);
  int s1 = lower_bound_batch(node_batch, b + 1);
  cnt[b] = s1 - s0;
}

// ---------------------------------------------------------------------------
// K4: scatter edge coefficients into t[row][batch[col]] (thread-per-edge).
// ---------------------------------------------------------------------------
__global__ __launch_bounds__(256) void k_t(
    const int* __restrict__ ei, const int* __restrict__ node_batch,
    const float* __restrict__ wbuf, const float* __restrict__ dis,
    float* __restrict__ t) {
  int e = blockIdx.x * 256 + threadIdx.x;
  if (e >= NEDGES) return;
  int r = ei[e], c = ei[NEDGES + e];
  float coeff = dis[r] * wbuf[e] * dis[c];
  int b = node_batch[c];
  unsafeAtomicAdd(&t[(size_t)r * BATCH + b], coeff);
}

// ---------------------------------------------------------------------------
// K5: part[bid][b][j] = sum_{n in block} t[n][b] * x[n][j]
//     Canonical LDS double-buffer GEMM (T14 issue-early/write-late staging):
//     chunk = 16 nodes (x 16KB + t 4KB in LDS, 2 buffers = 40KB -> 2 blk/CU).
//     Wave wid stages row wid; compute: lane = j-quad (ds_read_b128, dense),
//     wave = b-quad (uniform ds_read_b128 broadcast). 256 FMA per wave-chunk
//     hides the next chunk's global-load latency. Flush: plain coalesced
//     float4 stores to a PRIVATE slab (no atomics, no HBM RMW amplification).
// ---------------------------------------------------------------------------
__global__ __launch_bounds__(1024, 2) void k_gemm(
    const float* __restrict__ hidden, const int* __restrict__ node_idx,
    const float* __restrict__ t, float* __restrict__ part) {
  __shared__ float xbuf[2][CK][HDIM];   // 32 KB
  __shared__ float tbuf[2][CK][BATCH];  //  8 KB
  int tid  = threadIdx.x;
  int lane = tid & 63;
  int wid  = tid >> 6;          // 0..15 = staged row within chunk; b-quad 4*wid
  int n0   = blockIdx.x * NPB;
  float acc[4][4] = {{0.f}};

  // prologue: stage chunk 0
  {
    int nid = node_idx[n0 + wid];
    float4 xr = *((const float4*)(hidden + (size_t)nid * HDIM) + lane);
    float  tr = t[(size_t)(n0 + wid) * BATCH + lane];
    *((float4*)&xbuf[0][wid][4 * lane]) = xr;
    tbuf[0][wid][lane] = tr;
  }

  for (int c = 0; c < NC; ++c) {
    __syncthreads();                       // buf[c&1] staged & visible
    // issue next chunk's global loads NOW (consumed only after compute,
    // so latency hides under the 256 FMAs below)
    float4 xr2; float tr2;
    if (c + 1 < NC) {
      int nid2 = node_idx[n0 + (c + 1) * CK + wid];
      xr2 = *((const float4*)(hidden + (size_t)nid2 * HDIM) + lane);
      tr2 = t[(size_t)(n0 + (c + 1) * CK + wid) * BATCH + lane];
      __builtin_amdgcn_sched_barrier(0);   // pin: don't sink these loads
    }
    // compute chunk c from LDS
    #pragma unroll
    for (int k = 0; k < CK; ++k) {
      float4 tq = *((const float4*)&tbuf[c & 1][k][4 * wid]);   // uniform
      float4 xq = *((const float4*)&xbuf[c & 1][k][4 * lane]);  // dense
      acc[0][0] = fmaf(tq.x, xq.x, acc[0][0]);
      acc[0][1] = fmaf(tq.x, xq.y, acc[0][1]);
      acc[0][2] = fmaf(tq.x, xq.z, acc[0][2]);
      acc[0][3] = fmaf(tq.x, xq.w, acc[0][3]);
      acc[1][0] = fmaf(tq.y, xq.x, acc[1][0]);
      acc[1][1] = fmaf(tq.y, xq.y, acc[1][1]);
      acc[1][2] = fmaf(tq.y, xq.z, acc[1][2]);
      acc[1][3] = fmaf(tq.y, xq.w, acc[1][3]);
      acc[2][0] = fmaf(tq.z, xq.x, acc[2][0]);
      acc[2][1] = fmaf(tq.z, xq.y, acc[2][1]);
      acc[2][2] = fmaf(tq.z, xq.z, acc[2][2]);
      acc[2][3] = fmaf(tq.z, xq.w, acc[2][3]);
      acc[3][0] = fmaf(tq.w, xq.x, acc[3][0]);
      acc[3][1] = fmaf(tq.w, xq.y, acc[3][1]);
      acc[3][2] = fmaf(tq.w, xq.z, acc[3][2]);
      acc[3][3] = fmaf(tq.w, xq.w, acc[3][3]);
    }
    // write-late: ds_write the prefetched chunk into the other buffer.
    // Its last readers finished before THIS iteration's top barrier.
    if (c + 1 < NC) {
      *((float4*)&xbuf[(c + 1) & 1][wid][4 * lane]) = xr2;
      tbuf[(c + 1) & 1][wid][lane] = tr2;
    }
  }

  // atomic-free flush: private slab, fully coalesced (1KB per wave-instr)
  float* myp = part + (size_t)blockIdx.x * (BATCH * HDIM);
  #pragma unroll
  for (int bi = 0; bi < 4; ++bi) {
    float4 o; o.x = acc[bi][0]; o.y = acc[bi][1]; o.z = acc[bi][2]; o.w = acc[bi][3];
    *((float4*)(myp + (size_t)(4 * wid + bi) * HDIM + 4 * lane)) = o;
  }
}

// ---------------------------------------------------------------------------
// K5b: sum the 512 slabs -> agg[b][j].  4-way K-split; 2 atomics per cell.
// ---------------------------------------------------------------------------
__global__ __launch_bounds__(256) void k_reduce(
    const float* __restrict__ part, float* __restrict__ agg) {
  int slice = blockIdx.x >> 6;                        // 0..3
  int i = (blockIdx.x & 63) * 256 + threadIdx.x;      // cell 0..16383
  float s0 = 0.f, s1 = 0.f, s2 = 0.f, s3 = 0.f;
  int k0 = slice * 128;
  for (int k = k0; k < k0 + 128; k += 4) {
    s0 += part[(size_t)(k    ) * (BATCH * HDIM) + i];
    s1 += part[(size_t)(k + 1) * (BATCH * HDIM) + i];
    s2 += part[(size_t)(k + 2) * (BATCH * HDIM) + i];
    s3 += part[(size_t)(k + 3) * (BATCH * HDIM) + i];
  }
  unsafeAtomicAdd(&agg[i], (s0 + s1) + (s2 + s3));
}

// ---------------------------------------------------------------------------
// K6: one block per batch b.
//     pooled[k] = (Wc[k,:] . agg[b,:]) / cnt[b] + bc[k]
//     out[b][h] = tanh(Wd[h,:] . pooled + bd[h])
// ---------------------------------------------------------------------------
__global__ __launch_bounds__(256) void k_final(
    const float* __restrict__ agg, const int* __restrict__ cnt,
    const float* __restrict__ Wc, const float* __restrict__ bc,
    const float* __restrict__ Wd, const float* __restrict__ bd,
    float* __restrict__ out) {
  __shared__ float s_in[HDIM];
  __shared__ float s_mid[HDIM];
  int b = blockIdx.x, tid = threadIdx.x;
  s_in[tid] = agg[(size_t)b * HDIM + tid];
  __syncthreads();
  int lane = tid & 63, wid = tid >> 6;
  float inv = 1.0f / fmaxf((float)cnt[b], 1.0f);
  for (int kk = 0; kk < 64; ++kk) {
    int k = wid * 64 + kk;
    float4 wv = ((const float4*)(Wc + (size_t)k * HDIM))[lane];
    float4 av = ((const float4*)s_in)[lane];
    float p = wv.x*av.x + wv.y*av.y + wv.z*av.z + wv.w*av.w;
    #pragma unroll
    for (int off = 32; off > 0; off >>= 1) p += __shfl_down(p, off);
    if (lane == 0) s_mid[k] = p * inv + bc[k];
  }
  __syncthreads();
  for (int kk = 0; kk < 64; ++kk) {
    int k = wid * 64 + kk;
    float4 wv = ((const float4*)(Wd + (size_t)k * HDIM))[lane];
    float4 av = ((const float4*)s_mid)[lane];
    float p = wv.x*av.x + wv.y*av.y + wv.z*av.z + wv.w*av.w;
    #pragma unroll
    for (int off = 32; off > 0; off >>= 1) p += __shfl_down(p, off);
    if (lane == 0) out[b * HDIM + k] = tanhf(p + bd[k]);
  }
}

// ---------------------------------------------------------------------------
extern "C" void kernel_launch(void* const* d_in, const int* in_sizes, int n_in,
                              void* d_out, int out_size, void* d_ws, size_t ws_size,
                              hipStream_t stream) {
  const float* hidden     = (const float*)d_in[0];
  const int*   node_idx   = (const int*)  d_in[1];
  const int*   ei         = (const int*)  d_in[2];
  const int*   node_batch = (const int*)  d_in[3];
  const float* Wf         = (const float*)d_in[4];
  const float* bf         = (const float*)d_in[5];
  const float* Wc         = (const float*)d_in[6];
  const float* bc         = (const float*)d_in[7];
  const float* Wd         = (const float*)d_in[8];
  const float* bd         = (const float*)d_in[9];
  float* out = (float*)d_out;

  // workspace layout (floats)
  float* ws   = (float*)d_ws;
  float* t    = ws;                               // 4,194,304  (16.8 MB)
  float* agg  = t + (size_t)NNODES * BATCH;       // 16,384     ([b][j])
  float* deg  = agg + BATCH * HDIM;               // 65,536
  int*   cnt  = (int*)(deg + NNODES);             // 64
  float* u    = (float*)(cnt + 64);               // 65,536
  float* v    = u + NNODES;                       // 65,536
  float* dis  = v + NNODES;                       // 65,536
  float* wbuf = dis + NNODES;                     // 262,144
  float* part = wbuf + NEDGES;                    // 512*16,384 (33.6 MB)

  // zero t | agg | deg | cnt (contiguous). part is fully overwritten.
  (void)hipMemsetAsync(t, 0,
      ((size_t)NNODES * BATCH + BATCH * HDIM + NNODES + 64) * sizeof(float),
      stream);

  k_uv    <<<NNODES / 4,   256,  0, stream>>>(hidden, node_idx, Wf, u, v);
  k_edge_w<<<NEDGES / 256, 256,  0, stream>>>(ei, u, v, bf, wbuf, deg);
  k_dis   <<<NNODES / 256, 256,  0, stream>>>(node_batch, deg, dis, t);
  k_cnt   <<<1,            64,   0, stream>>>(node_batch, cnt);
  k_t     <<<NEDGES / 256, 256,  0, stream>>>(ei, node_batch, wbuf, dis, t);
  k_gemm  <<<NNODES / NPB, 1024, 0, stream>>>(hidden, node_idx, t, part);
  k_reduce<<<256,          256,  0, stream>>>(part, agg);
  k_final <<<BATCH,        256,  0, stream>>>(agg, cnt, Wc, bc, Wd, bd, out);
}

// Round 9
// 120.368 us; speedup vs baseline: 2.5578x; 1.5210x over previous
//
#include <hip/hip_runtime.h>
#include <hip/hip_bf16.h>

#define NNODES 65536
#define NEDGES 262144
#define BATCH  64
#define HDIM   256
#define NPB    128          // nodes per k_gemm block -> 512 blocks
#define CK     16           // nodes per LDS chunk
#define NC     (NPB / CK)   // 8 chunks per block

// ---------------------------------------------------------------------------
// K1: per-node u[n] = Wf[0:H] . x[n],  v[n] = Wf[H:2H] . x[n]
// ---------------------------------------------------------------------------
__global__ __launch_bounds__(256) void k_uv(
    const float* __restrict__ hidden, const int* __restrict__ node_idx,
    const float* __restrict__ Wf, float* __restrict__ u, float* __restrict__ v) {
  int gw   = (blockIdx.x * 256 + threadIdx.x) >> 6;   // global wave = node
  int lane = threadIdx.x & 63;
  if (gw >= NNODES) return;
  const float4* xr = (const float4*)(hidden + (size_t)node_idx[gw] * HDIM);
  float4 xv = xr[lane];
  float4 wa = ((const float4*)Wf)[lane];
  float4 wb = ((const float4*)Wf)[64 + lane];
  float su = xv.x*wa.x + xv.y*wa.y + xv.z*wa.z + xv.w*wa.w;
  float sv = xv.x*wb.x + xv.y*wb.y + xv.z*wb.z + xv.w*wb.w;
  #pragma unroll
  for (int off = 32; off > 0; off >>= 1) {
    su += __shfl_down(su, off);
    sv += __shfl_down(sv, off);
  }
  if (lane == 0) { u[gw] = su; v[gw] = sv; }
}

// ---------------------------------------------------------------------------
// K2: per-edge filter weight w_e = sigmoid(u[row]+v[col]+bf); deg[col] += w_e
// ---------------------------------------------------------------------------
__global__ __launch_bounds__(256) void k_edge_w(
    const int* __restrict__ ei, const float* __restrict__ u,
    const float* __restrict__ v, const float* __restrict__ bf,
    float* __restrict__ wbuf, float* __restrict__ deg) {
  int e = blockIdx.x * 256 + threadIdx.x;
  if (e >= NEDGES) return;
  int r = ei[e], c = ei[NEDGES + e];
  float t = u[r] + v[c] + bf[0];
  float w = 1.0f / (1.0f + __expf(-t));
  wbuf[e] = w;
  unsafeAtomicAdd(&deg[c], w);
}

// ---------------------------------------------------------------------------
// K3: dis[n] = rsqrt(deg[n]+1); self-loop weight into t. NO atomics.
// ---------------------------------------------------------------------------
__global__ __launch_bounds__(256) void k_dis(
    const int* __restrict__ node_batch, const float* __restrict__ deg,
    float* __restrict__ dis, float* __restrict__ t) {
  int n = blockIdx.x * 256 + threadIdx.x;
  if (n >= NNODES) return;
  float dn = rsqrtf(deg[n] + 1.0f);
  dis[n] = dn;
  t[(size_t)n * BATCH + node_batch[n]] = dn * dn;
}

// ---------------------------------------------------------------------------
// K3b: counts via binary search on the SORTED node_batch (64 threads total).
// ---------------------------------------------------------------------------
__device__ __forceinline__ int lower_bound_batch(const int* nb, int key) {
  int lo = 0, hi = NNODES;
  while (lo < hi) {
    int mid = (lo + hi) >> 1;
    if (nb[mid] < key) lo = mid + 1; else hi = mid;
  }
  return lo;
}

__global__ __launch_bounds__(64) void k_cnt(
    const int* __restrict__ node_batch, int* __restrict__ cnt) {
  int b = threadIdx.x;   // 0..63
  int s0 = lower_bound_batch(node_batch, b);
  int s1 = lower_bound_batch(node_batch, b + 1);
  cnt[b] = s1 - s0;
}

// ---------------------------------------------------------------------------
// K4: scatter edge coefficients into t[row][batch[col]] (thread-per-edge).
// ---------------------------------------------------------------------------
__global__ __launch_bounds__(256) void k_t(
    const int* __restrict__ ei, const int* __restrict__ node_batch,
    const float* __restrict__ wbuf, const float* __restrict__ dis,
    float* __restrict__ t) {
  int e = blockIdx.x * 256 + threadIdx.x;
  if (e >= NEDGES) return;
  int r = ei[e], c = ei[NEDGES + e];
  float coeff = dis[r] * wbuf[e] * dis[c];
  int b = node_batch[c];
  unsafeAtomicAdd(&t[(size_t)r * BATCH + b], coeff);
}

// ---------------------------------------------------------------------------
// K5: part[bid][b][j] = sum_{n in block} t[n][b] * x[n][j]
//     LDS double-buffer GEMM (unchanged from R7 -- dropped out of top-5).
// ---------------------------------------------------------------------------
__global__ __launch_bounds__(1024, 2) void k_gemm(
    const float* __restrict__ hidden, const int* __restrict__ node_idx,
    const float* __restrict__ t, float* __restrict__ part) {
  __shared__ float xbuf[2][CK][HDIM];   // 32 KB
  __shared__ float tbuf[2][CK][BATCH];  //  8 KB
  int tid  = threadIdx.x;
  int lane = tid & 63;
  int wid  = tid >> 6;          // 0..15 = staged row within chunk; b-quad 4*wid
  int n0   = blockIdx.x * NPB;
  float acc[4][4] = {{0.f}};

  // prologue: stage chunk 0
  {
    int nid = node_idx[n0 + wid];
    float4 xr = *((const float4*)(hidden + (size_t)nid * HDIM) + lane);
    float  tr = t[(size_t)(n0 + wid) * BATCH + lane];
    *((float4*)&xbuf[0][wid][4 * lane]) = xr;
    tbuf[0][wid][lane] = tr;
  }

  for (int c = 0; c < NC; ++c) {
    __syncthreads();                       // buf[c&1] staged & visible
    // issue next chunk's global loads NOW (consumed only after compute,
    // so latency hides under the 256 FMAs below)
    float4 xr2; float tr2;
    if (c + 1 < NC) {
      int nid2 = node_idx[n0 + (c + 1) * CK + wid];
      xr2 = *((const float4*)(hidden + (size_t)nid2 * HDIM) + lane);
      tr2 = t[(size_t)(n0 + (c + 1) * CK + wid) * BATCH + lane];
      __builtin_amdgcn_sched_barrier(0);   // pin: don't sink these loads
    }
    // compute chunk c from LDS
    #pragma unroll
    for (int k = 0; k < CK; ++k) {
      float4 tq = *((const float4*)&tbuf[c & 1][k][4 * wid]);   // uniform
      float4 xq = *((const float4*)&xbuf[c & 1][k][4 * lane]);  // dense
      acc[0][0] = fmaf(tq.x, xq.x, acc[0][0]);
      acc[0][1] = fmaf(tq.x, xq.y, acc[0][1]);
      acc[0][2] = fmaf(tq.x, xq.z, acc[0][2]);
      acc[0][3] = fmaf(tq.x, xq.w, acc[0][3]);
      acc[1][0] = fmaf(tq.y, xq.x, acc[1][0]);
      acc[1][1] = fmaf(tq.y, xq.y, acc[1][1]);
      acc[1][2] = fmaf(tq.y, xq.z, acc[1][2]);
      acc[1][3] = fmaf(tq.y, xq.w, acc[1][3]);
      acc[2][0] = fmaf(tq.z, xq.x, acc[2][0]);
      acc[2][1] = fmaf(tq.z, xq.y, acc[2][1]);
      acc[2][2] = fmaf(tq.z, xq.z, acc[2][2]);
      acc[2][3] = fmaf(tq.z, xq.w, acc[2][3]);
      acc[3][0] = fmaf(tq.w, xq.x, acc[3][0]);
      acc[3][1] = fmaf(tq.w, xq.y, acc[3][1]);
      acc[3][2] = fmaf(tq.w, xq.z, acc[3][2]);
      acc[3][3] = fmaf(tq.w, xq.w, acc[3][3]);
    }
    // write-late: ds_write the prefetched chunk into the other buffer.
    if (c + 1 < NC) {
      *((float4*)&xbuf[(c + 1) & 1][wid][4 * lane]) = xr2;
      tbuf[(c + 1) & 1][wid][lane] = tr2;
    }
  }

  // atomic-free flush: private slab, fully coalesced (1KB per wave-instr)
  float* myp = part + (size_t)blockIdx.x * (BATCH * HDIM);
  #pragma unroll
  for (int bi = 0; bi < 4; ++bi) {
    float4 o; o.x = acc[bi][0]; o.y = acc[bi][1]; o.z = acc[bi][2]; o.w = acc[bi][3];
    *((float4*)(myp + (size_t)(4 * wid + bi) * HDIM + 4 * lane)) = o;
  }
}

// ---------------------------------------------------------------------------
// K5b: sum the 512 slabs -> agg[b][j].  4-way K-split; 2 atomics per cell.
// ---------------------------------------------------------------------------
__global__ __launch_bounds__(256) void k_reduce(
    const float* __restrict__ part, float* __restrict__ agg) {
  int slice = blockIdx.x >> 6;                        // 0..3
  int i = (blockIdx.x & 63) * 256 + threadIdx.x;      // cell 0..16383
  float s0 = 0.f, s1 = 0.f, s2 = 0.f, s3 = 0.f;
  int k0 = slice * 128;
  for (int k = k0; k < k0 + 128; k += 4) {
    s0 += part[(size_t)(k    ) * (BATCH * HDIM) + i];
    s1 += part[(size_t)(k + 1) * (BATCH * HDIM) + i];
    s2 += part[(size_t)(k + 2) * (BATCH * HDIM) + i];
    s3 += part[(size_t)(k + 3) * (BATCH * HDIM) + i];
  }
  unsafeAtomicAdd(&agg[i], (s0 + s1) + (s2 + s3));
}

// ---------------------------------------------------------------------------
// K6a: pooled[b][k] = (Wc[k,:] . agg[b,:]) / cnt[b] + bc[k]
//      ONE WAVE PER OUTPUT ELEMENT (16384 waves = 4096 blocks): lane loads
//      float4 of each row (1KB coalesced), 4 FMA, 6-step shuffle reduce.
//      Replaces the 64-block serial k_final (was 92us at 2.8% occupancy).
// ---------------------------------------------------------------------------
__global__ __launch_bounds__(256) void k_mm1(
    const float* __restrict__ agg, const int* __restrict__ cnt,
    const float* __restrict__ Wc, const float* __restrict__ bc,
    float* __restrict__ pooled) {
  int gw   = (blockIdx.x * 256 + threadIdx.x) >> 6;   // 0..16383
  int lane = threadIdx.x & 63;
  int b = gw >> 8, k = gw & 255;
  float4 av = ((const float4*)(agg + (size_t)b * HDIM))[lane];
  float4 wv = ((const float4*)(Wc  + (size_t)k * HDIM))[lane];
  float p = av.x*wv.x + av.y*wv.y + av.z*wv.z + av.w*wv.w;
  #pragma unroll
  for (int off = 32; off > 0; off >>= 1) p += __shfl_down(p, off);
  if (lane == 0)
    pooled[(size_t)b * HDIM + k] = p / fmaxf((float)cnt[b], 1.0f) + bc[k];
}

// ---------------------------------------------------------------------------
// K6b: out[b][h] = tanh(Wd[h,:] . pooled[b,:] + bd[h])  -- same mapping
// ---------------------------------------------------------------------------
__global__ __launch_bounds__(256) void k_mm2(
    const float* __restrict__ pooled, const float* __restrict__ Wd,
    const float* __restrict__ bd, float* __restrict__ out) {
  int gw   = (blockIdx.x * 256 + threadIdx.x) >> 6;   // 0..16383
  int lane = threadIdx.x & 63;
  int b = gw >> 8, h = gw & 255;
  float4 av = ((const float4*)(pooled + (size_t)b * HDIM))[lane];
  float4 wv = ((const float4*)(Wd     + (size_t)h * HDIM))[lane];
  float p = av.x*wv.x + av.y*wv.y + av.z*wv.z + av.w*wv.w;
  #pragma unroll
  for (int off = 32; off > 0; off >>= 1) p += __shfl_down(p, off);
  if (lane == 0) out[(size_t)b * HDIM + h] = tanhf(p + bd[h]);
}

// ---------------------------------------------------------------------------
extern "C" void kernel_launch(void* const* d_in, const int* in_sizes, int n_in,
                              void* d_out, int out_size, void* d_ws, size_t ws_size,
                              hipStream_t stream) {
  const float* hidden     = (const float*)d_in[0];
  const int*   node_idx   = (const int*)  d_in[1];
  const int*   ei         = (const int*)  d_in[2];
  const int*   node_batch = (const int*)  d_in[3];
  const float* Wf         = (const float*)d_in[4];
  const float* bf         = (const float*)d_in[5];
  const float* Wc         = (const float*)d_in[6];
  const float* bc         = (const float*)d_in[7];
  const float* Wd         = (const float*)d_in[8];
  const float* bd         = (const float*)d_in[9];
  float* out = (float*)d_out;

  // workspace layout (floats)
  float* ws     = (float*)d_ws;
  float* t      = ws;                               // 4,194,304  (16.8 MB)
  float* agg    = t + (size_t)NNODES * BATCH;       // 16,384     ([b][j])
  float* deg    = agg + BATCH * HDIM;               // 65,536
  int*   cnt    = (int*)(deg + NNODES);             // 64
  float* u      = (float*)(cnt + 64);               // 65,536
  float* v      = u + NNODES;                       // 65,536
  float* dis    = v + NNODES;                       // 65,536
  float* wbuf   = dis + NNODES;                     // 262,144
  float* part   = wbuf + NEDGES;                    // 512*16,384 (33.6 MB)
  float* pooled = part + (size_t)(NNODES / NPB) * BATCH * HDIM;  // 16,384

  // zero t | agg | deg | cnt (contiguous). part/pooled fully overwritten.
  (void)hipMemsetAsync(t, 0,
      ((size_t)NNODES * BATCH + BATCH * HDIM + NNODES + 64) * sizeof(float),
      stream);

  k_uv    <<<NNODES / 4,   256,  0, stream>>>(hidden, node_idx, Wf, u, v);
  k_edge_w<<<NEDGES / 256, 256,  0, stream>>>(ei, u, v, bf, wbuf, deg);
  k_dis   <<<NNODES / 256, 256,  0, stream>>>(node_batch, deg, dis, t);
  k_cnt   <<<1,            64,   0, stream>>>(node_batch, cnt);
  k_t     <<<NEDGES / 256, 256,  0, stream>>>(ei, node_batch, wbuf, dis, t);
  k_gemm  <<<NNODES / NPB, 1024, 0, stream>>>(hidden, node_idx, t, part);
  k_reduce<<<256,          256,  0, stream>>>(part, agg);
  k_mm1   <<<4096,         256,  0, stream>>>(agg, cnt, Wc, bc, pooled);
  k_mm2   <<<4096,         256,  0, stream>>>(pooled, Wd, bd, out);
}